// Round 8
// baseline (257.654 us; speedup 1.0000x reference)
//
#include <hip/hip_runtime.h>
#include <math.h>

#define T_STEPS 16
#define NTOK 2048
#define WAVES_PER_BLOCK 8
#define BLOCK (WAVES_PER_BLOCK * 64)
#define NUNIT 16   // 16 units; unit j covers token blocks 2j and 2j+1 (128 tokens)

typedef _Float16 h2 __attribute__((ext_vector_type(2)));
typedef unsigned short us2 __attribute__((ext_vector_type(2)));
typedef short ss2 __attribute__((ext_vector_type(2)));
#define BC(T, x) __builtin_bit_cast(T, x)

__device__ __forceinline__ h2 splat16(float v) {
    h2 r; r.x = (_Float16)v; r.y = r.x; return r;
}

// One corner, two tokens at once (packed f16). Quake hack per half:
// y = 0x59ba - ((q>>1)&0x7fff)  (no cross-half borrow: masked operand < magic)
#define CORNER(Ex, Ey, ux, uy, dout) { \
    const h2 dx = BC(h2, Ex) + ux; \
    const h2 dy = BC(h2, Ey) + uy; \
    const h2 q  = dx * dx + dy * dy; \
    const unsigned y_ = 0x59ba59bau - ((BC(unsigned, q) >> 1) & 0x7fff7fffu); \
    dout = q * BC(h2, y_); }

// pass 1, one unit = blocks {2j, 2j+1}: ~35 packed VALU + 2 ds_read_b128.
// dt = {d~(tok in blk 2j), d~(tok in blk 2j+1)} -> stored directly, no repack.
#define PASS1(j, pk) { \
    const int sl = ((j) << 6) | lane; \
    const uint4 E0 = ldsP0[sl]; \
    const uint4 E1 = ldsP1[sl]; \
    h2 d0, d1, d2, d3; \
    CORNER(E0.x, E0.y, ux0, uy0, d0) \
    CORNER(E0.z, E0.w, ux1, uy1, d1) \
    CORNER(E1.x, E1.y, ux2, uy2, d2) \
    CORNER(E1.z, E1.w, ux3, uy3, d3) \
    const h2 dt = (d0 + d1) + (d2 + d3); \
    pk = BC(unsigned, dt); \
    pmin = __builtin_elementwise_min(pmin, BC(us2, dt)); \
    if (((j) & 3) == 3) __builtin_amdgcn_sched_barrier(0); }

// exact f32 eval of one 64-token block, codebook from global (L2-hot 64 KB)
#define EXACT(k) { \
    const int n = ((k) << 6) | lane; \
    const float4 A  = gsrc[2 * n]; \
    const float4 Bv = gsrc[2 * n + 1]; \
    float dx, dy; \
    dx = A.x  + u0x; dy = A.y  + u0y; const float q0 = fmaf(dy, dy, dx * dx); \
    dx = A.z  + u1x; dy = A.w  + u1y; const float q1 = fmaf(dy, dy, dx * dx); \
    dx = Bv.x + u2x; dy = Bv.y + u2y; const float q2 = fmaf(dy, dy, dx * dx); \
    dx = Bv.z + u3x; dy = Bv.w + u3y; const float q3 = fmaf(dy, dy, dx * dx); \
    const float d = (__builtin_amdgcn_sqrtf(q0) + __builtin_amdgcn_sqrtf(q1)) + \
                    (__builtin_amdgcn_sqrtf(q2) + __builtin_amdgcn_sqrtf(q3)); \
    const bool upd = (d < bestd) || (d == bestd && n < bestn); \
    bestd = upd ? d : bestd; \
    bestn = upd ? n : bestn; }

// pass 2 prescreen: packed i16 subtract (valid: both halves positive f16
// bit patterns < 0x8000), sign bits flag d~ < thr for either block.
#define PASS2(j, pk) { \
    const ss2 df = BC(ss2, pk) - BC(ss2, TT2); \
    if (__any((BC(unsigned, df) & 0x80008000u) != 0u)) { \
        if (__any(df.x < (short)0)) EXACT(2 * (j)) \
        if (__any(df.y < (short)0)) EXACT(2 * (j) + 1) } }

#define FOR_U(M) \
    M(0,pk00)  M(1,pk01)  M(2,pk02)  M(3,pk03)  M(4,pk04)  M(5,pk05)  M(6,pk06)  M(7,pk07) \
    M(8,pk08)  M(9,pk09)  M(10,pk10) M(11,pk11) M(12,pk12) M(13,pk13) M(14,pk14) M(15,pk15)

#define DECL_U(j, pk) unsigned pk;

__global__ __launch_bounds__(BLOCK)
void tokenizer_kernel(const float* __restrict__ data,
                      const float* __restrict__ tok,
                      float* __restrict__ out,
                      int B) {
    // unit j, lane l -> tokens n0=(2j)*64+l (low half) and n1=n0+64 (high half)
    __shared__ uint4 ldsP0[NUNIT * 64];   // corners 0,1: {x0pk, y0pk, x1pk, y1pk}
    __shared__ uint4 ldsP1[NUNIT * 64];   // corners 2,3
    __shared__ float4 s_step[WAVES_PER_BLOCK][T_STEPS];  // px, py, sin(h), cos(h)

    const float4* gsrc = (const float4*)tok;
    for (int slot = threadIdx.x; slot < NUNIT * 64; slot += BLOCK) {
        const int j = slot >> 6, l = slot & 63;
        const int n0 = ((2 * j) << 6) | l, n1 = n0 + 64;
        const float4 a0 = gsrc[2 * n0], b0 = gsrc[2 * n0 + 1];
        const float4 a1 = gsrc[2 * n1], b1 = gsrc[2 * n1 + 1];
        uint4 e0, e1;
        e0.x = BC(unsigned, __builtin_amdgcn_cvt_pkrtz(a0.x, a1.x));
        e0.y = BC(unsigned, __builtin_amdgcn_cvt_pkrtz(a0.y, a1.y));
        e0.z = BC(unsigned, __builtin_amdgcn_cvt_pkrtz(a0.z, a1.z));
        e0.w = BC(unsigned, __builtin_amdgcn_cvt_pkrtz(a0.w, a1.w));
        e1.x = BC(unsigned, __builtin_amdgcn_cvt_pkrtz(b0.x, b1.x));
        e1.y = BC(unsigned, __builtin_amdgcn_cvt_pkrtz(b0.y, b1.y));
        e1.z = BC(unsigned, __builtin_amdgcn_cvt_pkrtz(b0.z, b1.z));
        e1.w = BC(unsigned, __builtin_amdgcn_cvt_pkrtz(b0.w, b1.w));
        ldsP0[slot] = e0;
        ldsP1[slot] = e1;
    }

    const int wave = threadIdx.x >> 6;
    const int lane = threadIdx.x & 63;
    const int b = blockIdx.x * WAVES_PER_BLOCK + wave;
    const float* db = data + (size_t)b * (T_STEPS * 3);

    // hoisted per-step trig: 16 lanes compute the 16 steps' sincos in parallel
    if (b < B && lane < T_STEPS) {
        const float px = db[lane * 3 + 0];
        const float py = db[lane * 3 + 1];
        const float hh = db[lane * 3 + 2];
        float s_, c_;
        sincosf(hh, &s_, &c_);
        s_step[wave][lane] = make_float4(px, py, s_, c_);
    }
    __syncthreads();

    if (b >= B) return;

    float* outIdx  = out;
    float* outPos  = out + (size_t)B * T_STEPS;
    float* outHead = out + (size_t)B * T_STEPS * 3;

    float cpx = 0.f, cpy = 0.f;    // carry: prev_pos
    float rc = 1.f, rs = 0.f;      // carry: cos/sin(prev_head)

    for (int t = 0; t < T_STEPS; ++t) {
        const float4 st = s_step[wave][t];
        const float px = st.x, py = st.y, sh = st.z, ch = st.w;

        const float hc = 0.5f * ch, hs = 0.5f * sh;
        const float lc = 4.8f * hc, ls = 4.8f * hs;
        const float wc = 2.0f * hc, ws = 2.0f * hs;

        // e_j = cp - g_j ; u_j = R^T e_j  =>  dist_j = || f_j + u_j ||
        const float e0x = cpx - (px + lc - ws), e0y = cpy - (py + ls + wc);
        const float e1x = cpx - (px + lc + ws), e1y = cpy - (py + ls - wc);
        const float e2x = cpx - (px - lc + ws), e2y = cpy - (py - ls - wc);
        const float e3x = cpx - (px - lc - ws), e3y = cpy - (py - ls + wc);
        const float u0x = rc * e0x + rs * e0y, u0y = rc * e0y - rs * e0x;
        const float u1x = rc * e1x + rs * e1y, u1y = rc * e1y - rs * e1x;
        const float u2x = rc * e2x + rs * e2y, u2y = rc * e2y - rs * e2x;
        const float u3x = rc * e3x + rs * e3y, u3y = rc * e3y - rs * e3x;

        // broadcast u's to both packed halves (same u for both blocks of a unit)
        const h2 ux0 = splat16(u0x), uy0 = splat16(u0y);
        const h2 ux1 = splat16(u1x), uy1 = splat16(u1y);
        const h2 ux2 = splat16(u2x), uy2 = splat16(u2y);
        const h2 ux3 = splat16(u3x), uy3 = splat16(u3y);

        // ---- pass 1: packed approx d~, 2 blocks per op
        FOR_U(DECL_U)
        us2 pmin; pmin.x = (unsigned short)0x7bff; pmin.y = (unsigned short)0x7bff;
        FOR_U(PASS1)

        // wave-wide min on f16 bit patterns (positive => integer order == value order)
        const unsigned pm = BC(unsigned, pmin);
        unsigned dm = pm & 0xffffu;
        const unsigned hi16 = pm >> 16;
        dm = hi16 < dm ? hi16 : dm;
        #pragma unroll
        for (int off = 32; off > 0; off >>= 1) {
            const unsigned od = (unsigned)__shfl_xor((int)dm, off, 64);
            dm = od < dm ? od : dm;
        }
        const float dminf = (float)BC(_Float16, (unsigned short)dm);
        // slack: 3.42% hack + f16 rounding (rel) + cancellation (abs)
        const float thrf = fmaf(dminf, 1.35f, 0.25f);
        const unsigned short tb = BC(unsigned short, (_Float16)thrf);
        const unsigned TT2 = (unsigned)tb * 0x00010001u;

        // ---- pass 2: packed-int prescreen, exact f32 v_sqrt only where it fires
        float bestd = 3.4e38f;
        int   bestn = 0;
        FOR_U(PASS2)

        // wave argmin reduction, lowest-index tie-break (matches jnp.argmin)
        #pragma unroll
        for (int off = 32; off > 0; off >>= 1) {
            const float od = __shfl_xor(bestd, off, 64);
            const int   on = __shfl_xor(bestn, off, 64);
            if (od < bestd || (od == bestd && on < bestn)) { bestd = od; bestn = on; }
        }

        // selected contour in global frame (exact f32 codebook; same arithmetic
        // as the R1-passing version)
        const float4 A  = gsrc[2 * bestn];
        const float4 Bv = gsrc[2 * bestn + 1];
        const float c0x = A.x  * rc - A.y  * rs + cpx, c0y = A.x  * rs + A.y  * rc + cpy;
        const float c1x = A.z  * rc - A.w  * rs + cpx, c1y = A.z  * rs + A.w  * rc + cpy;
        const float c2x = Bv.x * rc - Bv.y * rs + cpx, c2y = Bv.x * rs + Bv.y * rc + cpy;
        const float c3x = Bv.z * rc - Bv.w * rs + cpx, c3y = Bv.z * rs + Bv.w * rc + cpy;

        const float npx = 0.25f * (((c0x + c1x) + c2x) + c3x);
        const float npy = 0.25f * (((c0y + c1y) + c2y) + c3y);
        const float dxx = c0x - c3x, dyy = c0y - c3y;

        // carry FIRST (critical path); outputs can schedule into next step
        cpx = npx; cpy = npy;
        const float len = __builtin_amdgcn_sqrtf(fmaf(dyy, dyy, dxx * dxx));
        rc = dxx / len;
        rs = dyy / len;

        const float nh = atan2f(dyy, dxx);
        if (lane == 0) {
            const int ot = b * T_STEPS + t;
            outIdx[ot]         = (float)bestn;
            outPos[2 * ot]     = npx;
            outPos[2 * ot + 1] = npy;
            outHead[ot]        = nh;
        }
    }
}

extern "C" void kernel_launch(void* const* d_in, const int* in_sizes, int n_in,
                              void* d_out, int out_size, void* d_ws, size_t ws_size,
                              hipStream_t stream) {
    const float* data = (const float*)d_in[0];
    const float* tok  = (const float*)d_in[1];
    float* out = (float*)d_out;

    const int B = in_sizes[0] / (T_STEPS * 3);   // 4096
    const int grid = (B + WAVES_PER_BLOCK - 1) / WAVES_PER_BLOCK;

    tokenizer_kernel<<<grid, BLOCK, 0, stream>>>(data, tok, out, B);
}

// Round 9
// 135.008 us; speedup vs baseline: 1.9084x; 1.9084x over previous
//
#include <hip/hip_runtime.h>
#include <math.h>

#define T_STEPS 16
#define NTOK 2048
#define WAVES_PER_BLOCK 8
#define BLOCK (WAVES_PER_BLOCK * 64)

typedef _Float16 h2 __attribute__((ext_vector_type(2)));
typedef unsigned short us2 __attribute__((ext_vector_type(2)));
#define BC(T, x) __builtin_bit_cast(T, x)

// Quake approx: sqrt(q) ~= q * rsqrt_hack(q); rel err <= 3.42%, 3 full-rate ops
__device__ __forceinline__ float approx_sqrt(float q) {
    float y = __uint_as_float(0x5f3759dfu - (__float_as_uint(q) >> 1));
    return q * y;
}

template<int CTRL>
__device__ __forceinline__ unsigned dpp_u32(unsigned v) {
    return (unsigned)__builtin_amdgcn_update_dpp((int)v, (int)v, CTRL, 0xf, 0xf, false);
}

// 64-lane u32 min via DPP (row_shr 1/2/4/8 + row_bcast15/31), ~12 full-rate ops.
// Result gathered in lane 63, broadcast via readlane.
__device__ __forceinline__ unsigned wave_min_u32(unsigned v) {
    unsigned t;
    t = dpp_u32<0x111>(v); v = t < v ? t : v;   // row_shr:1
    t = dpp_u32<0x112>(v); v = t < v ? t : v;   // row_shr:2
    t = dpp_u32<0x114>(v); v = t < v ? t : v;   // row_shr:4
    t = dpp_u32<0x118>(v); v = t < v ? t : v;   // row_shr:8
    t = dpp_u32<0x142>(v); v = t < v ? t : v;   // row_bcast:15
    t = dpp_u32<0x143>(v); v = t < v ? t : v;   // row_bcast:31
    return (unsigned)__builtin_amdgcn_readlane((int)v, 63);
}

// 64-lane packed-u16 elementwise min via DPP; returns min of both halves.
__device__ __forceinline__ unsigned wave_min_pk_u16(us2 v) {
#define STEPD(C) { const us2 t_ = BC(us2, dpp_u32<C>(BC(unsigned, v))); \
                   v = __builtin_elementwise_min(v, t_); }
    STEPD(0x111) STEPD(0x112) STEPD(0x114) STEPD(0x118) STEPD(0x142) STEPD(0x143)
#undef STEPD
    const unsigned r = (unsigned)__builtin_amdgcn_readlane((int)BC(unsigned, v), 63);
    const unsigned lo = r & 0xffffu, hi = r >> 16;
    return lo < hi ? lo : hi;
}

// polynomial atan2, |err| ~1e-4 rad; heading is an OUTPUT only (threshold 40.96),
// the recurrence carry uses the normalized edge vector, not this.
__device__ __forceinline__ float fast_atan2(float y, float x) {
    const float ax = fabsf(x), ay = fabsf(y);
    const float mx = fmaxf(ax, ay), mn = fminf(ax, ay);
    const float a = mn / mx;
    const float s = a * a;
    float r = fmaf(fmaf(fmaf(-0.0464964749f, s, 0.15931422f), s, -0.327622764f), s * a, a);
    if (ay > ax) r = 1.57079637f - r;
    if (x < 0.f) r = 3.14159274f - r;
    return y < 0.f ? -r : r;
}

// approx distance for one 64-token block (f32 math, R5-proven expressions)
#define DBLK(k, dreg) { \
    const float4 A  = ldsA[((k) << 6) | lane]; \
    const float4 Bv = ldsB[((k) << 6) | lane]; \
    float dx, dy; \
    dx = A.x  + u0x; dy = A.y  + u0y; const float q0 = fmaf(dy, dy, dx * dx); \
    dx = A.z  + u1x; dy = A.w  + u1y; const float q1 = fmaf(dy, dy, dx * dx); \
    dx = Bv.x + u2x; dy = Bv.y + u2y; const float q2 = fmaf(dy, dy, dx * dx); \
    dx = Bv.z + u3x; dy = Bv.w + u3y; const float q3 = fmaf(dy, dy, dx * dx); \
    dreg = (approx_sqrt(q0) + approx_sqrt(q1)) + (approx_sqrt(q2) + approx_sqrt(q3)); }

// pass 1 pair: blocks 2j, 2j+1 -> one packed u32 (RTZ: stored <= computed);
// sched_barrier every 2nd pair (4 ds_reads in flight, no hoist-spill)
#define PASS1(j, pk) { \
    float dA_, dB_; \
    DBLK(2*(j),   dA_) \
    DBLK(2*(j)+1, dB_) \
    pk = BC(unsigned, __builtin_amdgcn_cvt_pkrtz(dA_, dB_)); \
    pmin = __builtin_elementwise_min(pmin, BC(us2, pk)); \
    if ((j) & 1) __builtin_amdgcn_sched_barrier(0); }

// candidate-mask build: integer compare on positive f16 bit patterns
#define MASK(j, pk) { \
    const us2 v_ = BC(us2, pk); \
    if (v_.x <= tb) cmask |= (1u << (2*(j))); \
    if (v_.y <= tb) cmask |= (1u << (2*(j)+1)); }

#define FOR_U(M) \
    M(0,pk00)  M(1,pk01)  M(2,pk02)  M(3,pk03)  M(4,pk04)  M(5,pk05)  M(6,pk06)  M(7,pk07) \
    M(8,pk08)  M(9,pk09)  M(10,pk10) M(11,pk11) M(12,pk12) M(13,pk13) M(14,pk14) M(15,pk15)

#define DECL_U(j, pk) unsigned pk;

__global__ __launch_bounds__(BLOCK)
void tokenizer_kernel(const float* __restrict__ data,
                      const float* __restrict__ tok,
                      float* __restrict__ out,
                      int B) {
    __shared__ float4 ldsA[NTOK];   // corners 0,1: (x0,y0,x1,y1)
    __shared__ float4 ldsB[NTOK];   // corners 2,3: (x2,y2,x3,y3)
    __shared__ float4 s_step[WAVES_PER_BLOCK][T_STEPS];  // px, py, sin(h), cos(h)

    const float4* src = (const float4*)tok;
    for (int j = threadIdx.x; j < 2 * NTOK; j += BLOCK) {
        float4 v = src[j];
        if (j & 1) ldsB[j >> 1] = v;
        else       ldsA[j >> 1] = v;
    }

    const int wave = threadIdx.x >> 6;
    const int lane = threadIdx.x & 63;
    const int b = blockIdx.x * WAVES_PER_BLOCK + wave;
    const float* db = data + (size_t)b * (T_STEPS * 3);

    // hoisted per-step trig: 16 lanes compute the 16 steps' sincos in parallel
    if (b < B && lane < T_STEPS) {
        const float px = db[lane * 3 + 0];
        const float py = db[lane * 3 + 1];
        const float hh = db[lane * 3 + 2];
        float s_, c_;
        sincosf(hh, &s_, &c_);
        s_step[wave][lane] = make_float4(px, py, s_, c_);
    }
    __syncthreads();

    if (b >= B) return;

    float* outIdx  = out;
    float* outPos  = out + (size_t)B * T_STEPS;
    float* outHead = out + (size_t)B * T_STEPS * 3;

    float cpx = 0.f, cpy = 0.f;    // carry: prev_pos
    float rc = 1.f, rs = 0.f;      // carry: cos/sin(prev_head)

    for (int t = 0; t < T_STEPS; ++t) {
        const float4 st = s_step[wave][t];
        const float px = st.x, py = st.y, sh = st.z, ch = st.w;

        const float hc = 0.5f * ch, hs = 0.5f * sh;
        const float lc = 4.8f * hc, ls = 4.8f * hs;
        const float wc = 2.0f * hc, ws = 2.0f * hs;

        // e_j = cp - g_j ; u_j = R^T e_j  =>  dist_j = || f_j + u_j ||
        const float e0x = cpx - (px + lc - ws), e0y = cpy - (py + ls + wc);
        const float e1x = cpx - (px + lc + ws), e1y = cpy - (py + ls - wc);
        const float e2x = cpx - (px - lc + ws), e2y = cpy - (py - ls - wc);
        const float e3x = cpx - (px - lc - ws), e3y = cpy - (py - ls + wc);
        const float u0x = rc * e0x + rs * e0y, u0y = rc * e0y - rs * e0x;
        const float u1x = rc * e1x + rs * e1y, u1y = rc * e1y - rs * e1x;
        const float u2x = rc * e2x + rs * e2y, u2y = rc * e2y - rs * e2x;
        const float u3x = rc * e3x + rs * e3y, u3y = rc * e3y - rs * e3x;

        // ---- pass 1: f32 approx d~ for all tokens, f16-packed storage
        FOR_U(DECL_U)
        us2 pmin; pmin.x = (unsigned short)0x7fff; pmin.y = (unsigned short)0x7fff;
        FOR_U(PASS1)

        // wave-wide min via DPP (no bpermute cascades)
        const unsigned dm16 = wave_min_pk_u16(pmin);
        const float dminf = (float)BC(_Float16, (unsigned short)dm16);
        // sound slack: need >= (1.0342)/(0.9658) = 1.0708; 1.078 + 1ulp guard
        const float thrf = dminf * 1.078f;
        const unsigned short tb = (unsigned short)(BC(unsigned short, (_Float16)thrf) + 1);

        // ---- pass 2: per-lane candidate bitmask, exact f32 eval per firing token
        unsigned cmask = 0u;
        FOR_U(MASK)

        float bestd = 3.4e38f;
        int   bestn = 0x7fffffff;
        unsigned m = cmask;
        while (__any(m != 0u)) {
            if (m) {
                const int k = __builtin_ctz(m);
                m &= (m - 1u);
                const int n = (k << 6) | lane;
                const float4 A  = ldsA[n];
                const float4 Bv = ldsB[n];
                float dx, dy;
                dx = A.x  + u0x; dy = A.y  + u0y; const float q0 = fmaf(dy, dy, dx * dx);
                dx = A.z  + u1x; dy = A.w  + u1y; const float q1 = fmaf(dy, dy, dx * dx);
                dx = Bv.x + u2x; dy = Bv.y + u2y; const float q2 = fmaf(dy, dy, dx * dx);
                dx = Bv.z + u3x; dy = Bv.w + u3y; const float q3 = fmaf(dy, dy, dx * dx);
                const float d = (__builtin_amdgcn_sqrtf(q0) + __builtin_amdgcn_sqrtf(q1)) +
                                (__builtin_amdgcn_sqrtf(q2) + __builtin_amdgcn_sqrtf(q3));
                const bool upd = (d < bestd) || (d == bestd && n < bestn);
                bestd = upd ? d : bestd;
                bestn = upd ? n : bestn;
            }
        }

        // exact argmin across wave: DPP min on d-bits, then DPP min on index
        // among exact-min lanes (global lowest-index tie-break = jnp.argmin)
        const unsigned dbits = BC(unsigned, bestd);          // bestd >= 0, +inf ok
        const unsigned dminb = wave_min_u32(dbits);
        const unsigned candn = (dbits == dminb) ? (unsigned)bestn : 0x7fffffffu;
        const int nSel = (int)wave_min_u32(candn);

        // selected contour in global frame (same arithmetic as R1-passing version)
        const float4 A  = ldsA[nSel];
        const float4 Bv = ldsB[nSel];
        const float c0x = A.x  * rc - A.y  * rs + cpx, c0y = A.x  * rs + A.y  * rc + cpy;
        const float c1x = A.z  * rc - A.w  * rs + cpx, c1y = A.z  * rs + A.w  * rc + cpy;
        const float c2x = Bv.x * rc - Bv.y * rs + cpx, c2y = Bv.x * rs + Bv.y * rc + cpy;
        const float c3x = Bv.z * rc - Bv.w * rs + cpx, c3y = Bv.z * rs + Bv.w * rc + cpy;

        const float npx = 0.25f * (((c0x + c1x) + c2x) + c3x);
        const float npy = 0.25f * (((c0y + c1y) + c2y) + c3y);
        const float dxx = c0x - c3x, dyy = c0y - c3y;

        // carry FIRST (critical path into next step's scan)
        cpx = npx; cpy = npy;
        const float inv = __builtin_amdgcn_rsqf(fmaf(dyy, dyy, dxx * dxx));
        rc = dxx * inv;
        rs = dyy * inv;

        if (lane == 0) {
            const int ot = b * T_STEPS + t;
            outIdx[ot]         = (float)nSel;
            outPos[2 * ot]     = npx;
            outPos[2 * ot + 1] = npy;
            outHead[ot]        = fast_atan2(dyy, dxx);
        }
    }
}

extern "C" void kernel_launch(void* const* d_in, const int* in_sizes, int n_in,
                              void* d_out, int out_size, void* d_ws, size_t ws_size,
                              hipStream_t stream) {
    const float* data = (const float*)d_in[0];
    const float* tok  = (const float*)d_in[1];
    float* out = (float*)d_out;

    const int B = in_sizes[0] / (T_STEPS * 3);   // 4096
    const int grid = (B + WAVES_PER_BLOCK - 1) / WAVES_PER_BLOCK;

    tokenizer_kernel<<<grid, BLOCK, 0, stream>>>(data, tok, out, B);
}

// Round 10
// 107.475 us; speedup vs baseline: 2.3973x; 1.2562x over previous
//
#include <hip/hip_runtime.h>
#include <math.h>

#define T_STEPS 16
#define NTOK 2048
#define WAVES_PER_BLOCK 8
#define BLOCK (WAVES_PER_BLOCK * 64)
#define NUNIT 16   // unit j covers token blocks 2j (lo half) and 2j+1 (hi half)

typedef _Float16 h2 __attribute__((ext_vector_type(2)));
typedef unsigned short us2 __attribute__((ext_vector_type(2)));
#define BC(T, x) __builtin_bit_cast(T, x)

__device__ __forceinline__ h2 splat16(float v) {
    h2 r; r.x = (_Float16)v; r.y = r.x; return r;
}

template<int CTRL>
__device__ __forceinline__ unsigned dpp_u32(unsigned v) {
    return (unsigned)__builtin_amdgcn_update_dpp((int)v, (int)v, CTRL, 0xf, 0xf, false);
}

// 64-lane u32 min via DPP (row_shr 1/2/4/8 + row_bcast15/31) + readlane 63
__device__ __forceinline__ unsigned wave_min_u32(unsigned v) {
    unsigned t;
    t = dpp_u32<0x111>(v); v = t < v ? t : v;
    t = dpp_u32<0x112>(v); v = t < v ? t : v;
    t = dpp_u32<0x114>(v); v = t < v ? t : v;
    t = dpp_u32<0x118>(v); v = t < v ? t : v;
    t = dpp_u32<0x142>(v); v = t < v ? t : v;
    t = dpp_u32<0x143>(v); v = t < v ? t : v;
    return (unsigned)__builtin_amdgcn_readlane((int)v, 63);
}

// 64-lane packed-u16 elementwise min via DPP; returns min of both halves
__device__ __forceinline__ unsigned wave_min_pk_u16(us2 v) {
#define STEPD(C) { const us2 t_ = BC(us2, dpp_u32<C>(BC(unsigned, v))); \
                   v = __builtin_elementwise_min(v, t_); }
    STEPD(0x111) STEPD(0x112) STEPD(0x114) STEPD(0x118) STEPD(0x142) STEPD(0x143)
#undef STEPD
    const unsigned r = (unsigned)__builtin_amdgcn_readlane((int)BC(unsigned, v), 63);
    const unsigned lo = r & 0xffffu, hi = r >> 16;
    return lo < hi ? lo : hi;
}

// polynomial atan2, |err| ~1e-4 rad; heading is output-only (carry uses edge)
__device__ __forceinline__ float fast_atan2(float y, float x) {
    const float ax = fabsf(x), ay = fabsf(y);
    const float mx = fmaxf(ax, ay), mn = fminf(ax, ay);
    const float a = mn / mx;
    const float s = a * a;
    float r = fmaf(fmaf(fmaf(-0.0464964749f, s, 0.15931422f), s, -0.327622764f), s * a, a);
    if (ay > ax) r = 1.57079637f - r;
    if (x < 0.f) r = 3.14159274f - r;
    return y < 0.f ? -r : r;
}

// One corner, two token-blocks at once (packed f16). Quake hack per half:
// y = 0x59ba - ((q>>1)&0x7fff); borrow-free: masked operand <= 0x3dff < 0x59ba
#define CORNER(Ex, Ey, ux, uy, dout) { \
    const h2 dx = BC(h2, Ex) + ux; \
    const h2 dy = BC(h2, Ey) + uy; \
    const h2 q  = dx * dx + dy * dy; \
    const unsigned y_ = 0x59ba59bau - ((BC(unsigned, q) >> 1) & 0x7fff7fffu); \
    dout = q * BC(h2, y_); }

// pass 1, one unit = blocks {2j, 2j+1}: 2 ds_read_b128 + ~37 packed VALU
#define PASS1(j, pk) { \
    const int sl = ((j) << 6) | lane; \
    const uint4 E0 = ldsP0[sl]; \
    const uint4 E1 = ldsP1[sl]; \
    h2 d0, d1, d2, d3; \
    CORNER(E0.x, E0.y, ux0, uy0, d0) \
    CORNER(E0.z, E0.w, ux1, uy1, d1) \
    CORNER(E1.x, E1.y, ux2, uy2, d2) \
    CORNER(E1.z, E1.w, ux3, uy3, d3) \
    const h2 dt = (d0 + d1) + (d2 + d3); \
    pk = BC(unsigned, dt); \
    pmin = __builtin_elementwise_min(pmin, BC(us2, dt)); \
    if ((j) & 1) __builtin_amdgcn_sched_barrier(0); }

// candidate-mask: integer compare on positive f16 bit patterns (monotone)
#define MASK(j, pk) { \
    const us2 v_ = BC(us2, pk); \
    if (v_.x <= tb) cmask |= (1u << (2*(j))); \
    if (v_.y <= tb) cmask |= (1u << (2*(j)+1)); }

#define FOR_U(M) \
    M(0,pk00)  M(1,pk01)  M(2,pk02)  M(3,pk03)  M(4,pk04)  M(5,pk05)  M(6,pk06)  M(7,pk07) \
    M(8,pk08)  M(9,pk09)  M(10,pk10) M(11,pk11) M(12,pk12) M(13,pk13) M(14,pk14) M(15,pk15)

#define DECL_U(j, pk) unsigned pk;

__global__ __launch_bounds__(BLOCK)
void tokenizer_kernel(const float* __restrict__ data,
                      const float* __restrict__ tok,
                      float* __restrict__ out,
                      int B) {
    // f16 codebook only: 32 KB total -> 4 blocks/CU occupancy
    __shared__ uint4 ldsP0[NUNIT * 64];   // corners 0,1: {x0pk,y0pk,x1pk,y1pk}
    __shared__ uint4 ldsP1[NUNIT * 64];   // corners 2,3
    __shared__ float4 s_step[WAVES_PER_BLOCK][T_STEPS];  // px, py, sin, cos

    const float4* gsrc = (const float4*)tok;
    for (int slot = threadIdx.x; slot < NUNIT * 64; slot += BLOCK) {
        const int j = slot >> 6, l = slot & 63;
        const int n0 = ((2 * j) << 6) | l, n1 = n0 + 64;
        const float4 a0 = gsrc[2 * n0], b0 = gsrc[2 * n0 + 1];
        const float4 a1 = gsrc[2 * n1], b1 = gsrc[2 * n1 + 1];
        uint4 e0, e1;
        e0.x = BC(unsigned, __builtin_amdgcn_cvt_pkrtz(a0.x, a1.x));
        e0.y = BC(unsigned, __builtin_amdgcn_cvt_pkrtz(a0.y, a1.y));
        e0.z = BC(unsigned, __builtin_amdgcn_cvt_pkrtz(a0.z, a1.z));
        e0.w = BC(unsigned, __builtin_amdgcn_cvt_pkrtz(a0.w, a1.w));
        e1.x = BC(unsigned, __builtin_amdgcn_cvt_pkrtz(b0.x, b1.x));
        e1.y = BC(unsigned, __builtin_amdgcn_cvt_pkrtz(b0.y, b1.y));
        e1.z = BC(unsigned, __builtin_amdgcn_cvt_pkrtz(b0.z, b1.z));
        e1.w = BC(unsigned, __builtin_amdgcn_cvt_pkrtz(b0.w, b1.w));
        ldsP0[slot] = e0;
        ldsP1[slot] = e1;
    }

    const int wave = threadIdx.x >> 6;
    const int lane = threadIdx.x & 63;
    const int b = blockIdx.x * WAVES_PER_BLOCK + wave;
    const float* db = data + (size_t)b * (T_STEPS * 3);

    // hoisted per-step trig: 16 lanes compute the 16 steps' sincos in parallel
    if (b < B && lane < T_STEPS) {
        const float px = db[lane * 3 + 0];
        const float py = db[lane * 3 + 1];
        const float hh = db[lane * 3 + 2];
        float s_, c_;
        sincosf(hh, &s_, &c_);
        s_step[wave][lane] = make_float4(px, py, s_, c_);
    }
    __syncthreads();

    if (b >= B) return;

    float* outIdx  = out;
    float* outPos  = out + (size_t)B * T_STEPS;
    float* outHead = out + (size_t)B * T_STEPS * 3;

    float cpx = 0.f, cpy = 0.f;    // carry: prev_pos
    float rc = 1.f, rs = 0.f;      // carry: cos/sin(prev_head)

    for (int t = 0; t < T_STEPS; ++t) {
        const float4 st = s_step[wave][t];
        const float px = st.x, py = st.y, sh = st.z, ch = st.w;

        const float hc = 0.5f * ch, hs = 0.5f * sh;
        const float lc = 4.8f * hc, ls = 4.8f * hs;
        const float wc = 2.0f * hc, ws = 2.0f * hs;

        // e_j = cp - g_j ; u_j = R^T e_j  =>  dist_j = || f_j + u_j ||
        const float e0x = cpx - (px + lc - ws), e0y = cpy - (py + ls + wc);
        const float e1x = cpx - (px + lc + ws), e1y = cpy - (py + ls - wc);
        const float e2x = cpx - (px - lc + ws), e2y = cpy - (py - ls - wc);
        const float e3x = cpx - (px - lc - ws), e3y = cpy - (py - ls + wc);
        const float u0x = rc * e0x + rs * e0y, u0y = rc * e0y - rs * e0x;
        const float u1x = rc * e1x + rs * e1y, u1y = rc * e1y - rs * e1x;
        const float u2x = rc * e2x + rs * e2y, u2y = rc * e2y - rs * e2x;
        const float u3x = rc * e3x + rs * e3y, u3y = rc * e3y - rs * e3x;

        // packed-f16 u vectors (same u for both blocks of a unit)
        const h2 ux0 = splat16(u0x), uy0 = splat16(u0y);
        const h2 ux1 = splat16(u1x), uy1 = splat16(u1y);
        const h2 ux2 = splat16(u2x), uy2 = splat16(u2y);
        const h2 ux3 = splat16(u3x), uy3 = splat16(u3y);

        // ---- pass 1: packed-f16 approx d~, 2 blocks per op
        FOR_U(DECL_U)
        us2 pmin; pmin.x = (unsigned short)0x7fff; pmin.y = (unsigned short)0x7fff;
        FOR_U(PASS1)

        // wave-wide min via DPP
        const unsigned dm16 = wave_min_pk_u16(pmin);
        const float dminf = (float)BC(_Float16, (unsigned short)dm16);
        // slack: hack 3.42% rel (both sides) + f16 input rounding ~0.07 abs:
        // thr = 1.10*dmin + 0.15 covers worst case with margin (see analysis)
        const float thrf = fmaf(dminf, 1.10f, 0.15f);
        const unsigned short tb = (unsigned short)(BC(unsigned short, (_Float16)thrf) + 1);

        // ---- pass 2: per-lane candidate bitmask; exact f32 eval from global
        unsigned cmask = 0u;
        FOR_U(MASK)

        float bestd = 3.4e38f;
        int   bestn = 0x7fffffff;
        unsigned m = cmask;
        while (__any(m != 0u)) {
            if (m) {
                const int k = __builtin_ctz(m);
                m &= (m - 1u);
                const int n = (k << 6) | lane;
                const float4 A  = gsrc[2 * n];
                const float4 Bv = gsrc[2 * n + 1];
                float dx, dy;
                dx = A.x  + u0x; dy = A.y  + u0y; const float q0 = fmaf(dy, dy, dx * dx);
                dx = A.z  + u1x; dy = A.w  + u1y; const float q1 = fmaf(dy, dy, dx * dx);
                dx = Bv.x + u2x; dy = Bv.y + u2y; const float q2 = fmaf(dy, dy, dx * dx);
                dx = Bv.z + u3x; dy = Bv.w + u3y; const float q3 = fmaf(dy, dy, dx * dx);
                const float d = (__builtin_amdgcn_sqrtf(q0) + __builtin_amdgcn_sqrtf(q1)) +
                                (__builtin_amdgcn_sqrtf(q2) + __builtin_amdgcn_sqrtf(q3));
                const bool upd = (d < bestd) || (d == bestd && n < bestn);
                bestd = upd ? d : bestd;
                bestn = upd ? n : bestn;
            }
        }

        // exact argmin across wave: DPP min on d-bits, then lowest index among minima
        const unsigned dbits = BC(unsigned, bestd);
        const unsigned dminb = wave_min_u32(dbits);
        const unsigned candn = (dbits == dminb) ? (unsigned)bestn : 0x7fffffffu;
        const int nSel = (int)wave_min_u32(candn);

        // selected contour in global frame (exact f32 codebook from L2)
        const float4 A  = gsrc[2 * nSel];
        const float4 Bv = gsrc[2 * nSel + 1];
        const float c0x = A.x  * rc - A.y  * rs + cpx, c0y = A.x  * rs + A.y  * rc + cpy;
        const float c1x = A.z  * rc - A.w  * rs + cpx, c1y = A.z  * rs + A.w  * rc + cpy;
        const float c2x = Bv.x * rc - Bv.y * rs + cpx, c2y = Bv.x * rs + Bv.y * rc + cpy;
        const float c3x = Bv.z * rc - Bv.w * rs + cpx, c3y = Bv.z * rs + Bv.w * rc + cpy;

        const float npx = 0.25f * (((c0x + c1x) + c2x) + c3x);
        const float npy = 0.25f * (((c0y + c1y) + c2y) + c3y);
        const float dxx = c0x - c3x, dyy = c0y - c3y;

        // carry FIRST (critical path into next step's scan)
        cpx = npx; cpy = npy;
        const float inv = __builtin_amdgcn_rsqf(fmaf(dyy, dyy, dxx * dxx));
        rc = dxx * inv;
        rs = dyy * inv;

        if (lane == 0) {
            const int ot = b * T_STEPS + t;
            outIdx[ot]         = (float)nSel;
            outPos[2 * ot]     = npx;
            outPos[2 * ot + 1] = npy;
            outHead[ot]        = fast_atan2(dyy, dxx);
        }
    }
}

extern "C" void kernel_launch(void* const* d_in, const int* in_sizes, int n_in,
                              void* d_out, int out_size, void* d_ws, size_t ws_size,
                              hipStream_t stream) {
    const float* data = (const float*)d_in[0];
    const float* tok  = (const float*)d_in[1];
    float* out = (float*)d_out;

    const int B = in_sizes[0] / (T_STEPS * 3);   // 4096
    const int grid = (B + WAVES_PER_BLOCK - 1) / WAVES_PER_BLOCK;

    tokenizer_kernel<<<grid, BLOCK, 0, stream>>>(data, tok, out, B);
}

// Round 12
// 104.557 us; speedup vs baseline: 2.4643x; 1.0279x over previous
//
#include <hip/hip_runtime.h>
#include <math.h>

#define T_STEPS 16
#define NTOK 2048
#define WAVES_PER_BLOCK 8
#define BLOCK (WAVES_PER_BLOCK * 64)
#define NUNIT 16   // unit j covers token blocks 2j (lo half) and 2j+1 (hi half)

#define BC(T, x) __builtin_bit_cast(T, x)

// ---- forced-VOP3P helpers (defeat potential f16-vector scalarization) ----
__device__ __forceinline__ unsigned pk_min_u16(unsigned a, unsigned b) {
    unsigned r;
    asm("v_pk_min_u16 %0, %1, %2" : "=v"(r) : "v"(a), "v"(b));
    return r;
}
__device__ __forceinline__ unsigned pk_add_f16(unsigned a, unsigned b) {
    unsigned r;
    asm("v_pk_add_f16 %0, %1, %2" : "=v"(r) : "v"(a), "v"(b));
    return r;
}

// One corner, two token-blocks at once. 4 packed f16 ops + 3 int VOP2:
// q = (Ex+ux)^2 + (Ey+uy)^2 (packed); sqrt via f16 bit-hack per half:
// bits = ((q>>1) & 0x7fff7fff) + 0x1DE91DE9  (err in [-1.1%, +4.5%], checked
// at q=1,2,4,8; borrow/carry-free: masked half <= 0x3e00, +0x1de9 < 0x8000).
// NOTE operand binding: %3=Ex %4=Ey %5=ux %6=uy — R11's bug was %3+%4 here.
__device__ __forceinline__ unsigned corner16(unsigned Ex, unsigned Ey,
                                             unsigned ux, unsigned uy) {
    unsigned dx, dy, q;
    asm("v_pk_add_f16 %0, %3, %5\n\t"
        "v_pk_add_f16 %1, %4, %6\n\t"
        "v_pk_mul_f16 %2, %0, %0\n\t"
        "v_pk_fma_f16 %2, %1, %1, %2\n\t"
        "v_lshrrev_b32 %2, 1, %2\n\t"
        "v_and_b32 %2, 0x7fff7fff, %2\n\t"
        "v_add_u32 %2, 0x1de91de9, %2"
        : "=&v"(dx), "=&v"(dy), "=&v"(q)
        : "v"(Ex), "v"(Ey), "v"(ux), "v"(uy));
    return q;
}

template<int CTRL>
__device__ __forceinline__ unsigned dpp_u32(unsigned v) {
    return (unsigned)__builtin_amdgcn_update_dpp((int)v, (int)v, CTRL, 0xf, 0xf, false);
}

// 64-lane u32 min via DPP (row_shr 1/2/4/8 + row_bcast15/31) + readlane 63
__device__ __forceinline__ unsigned wave_min_u32(unsigned v) {
    unsigned t;
    t = dpp_u32<0x111>(v); v = t < v ? t : v;
    t = dpp_u32<0x112>(v); v = t < v ? t : v;
    t = dpp_u32<0x114>(v); v = t < v ? t : v;
    t = dpp_u32<0x118>(v); v = t < v ? t : v;
    t = dpp_u32<0x142>(v); v = t < v ? t : v;
    t = dpp_u32<0x143>(v); v = t < v ? t : v;
    return (unsigned)__builtin_amdgcn_readlane((int)v, 63);
}

// 64-lane packed-u16 min via DPP with forced v_pk_min_u16 combiner
__device__ __forceinline__ unsigned wave_min_pk(unsigned v) {
    v = pk_min_u16(v, dpp_u32<0x111>(v));
    v = pk_min_u16(v, dpp_u32<0x112>(v));
    v = pk_min_u16(v, dpp_u32<0x114>(v));
    v = pk_min_u16(v, dpp_u32<0x118>(v));
    v = pk_min_u16(v, dpp_u32<0x142>(v));
    v = pk_min_u16(v, dpp_u32<0x143>(v));
    const unsigned r = (unsigned)__builtin_amdgcn_readlane((int)v, 63);
    const unsigned lo = r & 0xffffu, hi = r >> 16;
    return lo < hi ? lo : hi;
}

// polynomial atan2, |err| ~1e-4 rad; heading is output-only (carry uses edge)
__device__ __forceinline__ float fast_atan2(float y, float x) {
    const float ax = fabsf(x), ay = fabsf(y);
    const float mx = fmaxf(ax, ay), mn = fminf(ax, ay);
    const float a = mn / mx;
    const float s = a * a;
    float r = fmaf(fmaf(fmaf(-0.0464964749f, s, 0.15931422f), s, -0.327622764f), s * a, a);
    if (ay > ax) r = 1.57079637f - r;
    if (x < 0.f) r = 3.14159274f - r;
    return y < 0.f ? -r : r;
}

__device__ __forceinline__ unsigned splatpk(float v) {
    return BC(unsigned, __builtin_amdgcn_cvt_pkrtz(v, v));
}

// pass 1, one unit = blocks {2j, 2j+1}: 2 ds_read_b128 + 32 forced-packed VALU
#define PASS1(j, pk) { \
    const int sl = ((j) << 6) | lane; \
    const uint4 E0 = ldsP0[sl]; \
    const uint4 E1 = ldsP1[sl]; \
    const unsigned d0 = corner16(E0.x, E0.y, ux0, uy0); \
    const unsigned d1 = corner16(E0.z, E0.w, ux1, uy1); \
    const unsigned d2 = corner16(E1.x, E1.y, ux2, uy2); \
    const unsigned d3 = corner16(E1.z, E1.w, ux3, uy3); \
    pk = pk_add_f16(pk_add_f16(d0, d1), pk_add_f16(d2, d3)); \
    pmin = pk_min_u16(pmin, pk); \
    if ((j) & 1) __builtin_amdgcn_sched_barrier(0); }

// candidate-mask: integer compare on positive f16 bit patterns (monotone)
#define MASK(j, pk) { \
    if ((pk & 0xffffu) <= tb32) cmask |= (1u << (2*(j))); \
    if ((pk >> 16)     <= tb32) cmask |= (1u << (2*(j)+1)); }

#define FOR_U(M) \
    M(0,pk00)  M(1,pk01)  M(2,pk02)  M(3,pk03)  M(4,pk04)  M(5,pk05)  M(6,pk06)  M(7,pk07) \
    M(8,pk08)  M(9,pk09)  M(10,pk10) M(11,pk11) M(12,pk12) M(13,pk13) M(14,pk14) M(15,pk15)

#define DECL_U(j, pk) unsigned pk;

__global__ __launch_bounds__(BLOCK)
void tokenizer_kernel(const float* __restrict__ data,
                      const float* __restrict__ tok,
                      float* __restrict__ out,
                      int B) {
    // f16 codebook only: 32 KB
    __shared__ uint4 ldsP0[NUNIT * 64];   // corners 0,1: {x0pk,y0pk,x1pk,y1pk}
    __shared__ uint4 ldsP1[NUNIT * 64];   // corners 2,3
    __shared__ float4 s_step[WAVES_PER_BLOCK][T_STEPS];  // px, py, sin, cos

    const float4* gsrc = (const float4*)tok;
    for (int slot = threadIdx.x; slot < NUNIT * 64; slot += BLOCK) {
        const int j = slot >> 6, l = slot & 63;
        const int n0 = ((2 * j) << 6) | l, n1 = n0 + 64;
        const float4 a0 = gsrc[2 * n0], b0 = gsrc[2 * n0 + 1];
        const float4 a1 = gsrc[2 * n1], b1 = gsrc[2 * n1 + 1];
        uint4 e0, e1;
        e0.x = BC(unsigned, __builtin_amdgcn_cvt_pkrtz(a0.x, a1.x));
        e0.y = BC(unsigned, __builtin_amdgcn_cvt_pkrtz(a0.y, a1.y));
        e0.z = BC(unsigned, __builtin_amdgcn_cvt_pkrtz(a0.z, a1.z));
        e0.w = BC(unsigned, __builtin_amdgcn_cvt_pkrtz(a0.w, a1.w));
        e1.x = BC(unsigned, __builtin_amdgcn_cvt_pkrtz(b0.x, b1.x));
        e1.y = BC(unsigned, __builtin_amdgcn_cvt_pkrtz(b0.y, b1.y));
        e1.z = BC(unsigned, __builtin_amdgcn_cvt_pkrtz(b0.z, b1.z));
        e1.w = BC(unsigned, __builtin_amdgcn_cvt_pkrtz(b0.w, b1.w));
        ldsP0[slot] = e0;
        ldsP1[slot] = e1;
    }

    const int wave = threadIdx.x >> 6;
    const int lane = threadIdx.x & 63;
    const int b = blockIdx.x * WAVES_PER_BLOCK + wave;
    const float* db = data + (size_t)b * (T_STEPS * 3);

    // hoisted per-step trig: 16 lanes compute the 16 steps' sincos in parallel
    if (b < B && lane < T_STEPS) {
        const float px = db[lane * 3 + 0];
        const float py = db[lane * 3 + 1];
        const float hh = db[lane * 3 + 2];
        float s_, c_;
        sincosf(hh, &s_, &c_);
        s_step[wave][lane] = make_float4(px, py, s_, c_);
    }
    __syncthreads();

    if (b >= B) return;

    float* outIdx  = out;
    float* outPos  = out + (size_t)B * T_STEPS;
    float* outHead = out + (size_t)B * T_STEPS * 3;

    float cpx = 0.f, cpy = 0.f;    // carry: prev_pos
    float rc = 1.f, rs = 0.f;      // carry: cos/sin(prev_head)

    for (int t = 0; t < T_STEPS; ++t) {
        const float4 st = s_step[wave][t];
        const float px = st.x, py = st.y, sh = st.z, ch = st.w;

        const float hc = 0.5f * ch, hs = 0.5f * sh;
        const float lc = 4.8f * hc, ls = 4.8f * hs;
        const float wc = 2.0f * hc, ws = 2.0f * hs;

        // e_j = cp - g_j ; u_j = R^T e_j  =>  dist_j = || f_j + u_j ||
        const float e0x = cpx - (px + lc - ws), e0y = cpy - (py + ls + wc);
        const float e1x = cpx - (px + lc + ws), e1y = cpy - (py + ls - wc);
        const float e2x = cpx - (px - lc + ws), e2y = cpy - (py - ls - wc);
        const float e3x = cpx - (px - lc - ws), e3y = cpy - (py - ls + wc);
        const float u0x = rc * e0x + rs * e0y, u0y = rc * e0y - rs * e0x;
        const float u1x = rc * e1x + rs * e1y, u1y = rc * e1y - rs * e1x;
        const float u2x = rc * e2x + rs * e2y, u2y = rc * e2y - rs * e2x;
        const float u3x = rc * e3x + rs * e3y, u3y = rc * e3y - rs * e3x;

        // packed-f16 u vectors (same u in both halves of a unit)
        const unsigned ux0 = splatpk(u0x), uy0 = splatpk(u0y);
        const unsigned ux1 = splatpk(u1x), uy1 = splatpk(u1y);
        const unsigned ux2 = splatpk(u2x), uy2 = splatpk(u2y);
        const unsigned ux3 = splatpk(u3x), uy3 = splatpk(u3y);

        // ---- pass 1: forced-packed approx d~, 2 blocks per lane-op
        FOR_U(DECL_U)
        unsigned pmin = 0x7fff7fffu;
        FOR_U(PASS1)

        // wave-wide min via DPP
        const unsigned dm16 = wave_min_pk(pmin);
        const float dminf = (float)BC(_Float16, (unsigned short)dm16);
        // slack: hack err [-1.1%,+4.5%] + f16 rounding; alpha=1.13 covers
        // eps<=6.1% rel, beta=0.18 covers abs input-rounding slack
        const float thrf = fmaf(dminf, 1.13f, 0.18f);
        const unsigned tb32 =
            (unsigned)BC(unsigned short, (_Float16)thrf) + 1u;

        // ---- pass 2: per-lane candidate bitmask; exact f32 eval from global
        unsigned cmask = 0u;
        FOR_U(MASK)

        float bestd = 3.4e38f;
        int   bestn = 0x7fffffff;
        unsigned m = cmask;
        while (__any(m != 0u)) {
            if (m) {
                const int k = __builtin_ctz(m);
                m &= (m - 1u);
                const int n = (k << 6) | lane;
                const float4 A  = gsrc[2 * n];
                const float4 Bv = gsrc[2 * n + 1];
                float dx, dy;
                dx = A.x  + u0x; dy = A.y  + u0y; const float q0 = fmaf(dy, dy, dx * dx);
                dx = A.z  + u1x; dy = A.w  + u1y; const float q1 = fmaf(dy, dy, dx * dx);
                dx = Bv.x + u2x; dy = Bv.y + u2y; const float q2 = fmaf(dy, dy, dx * dx);
                dx = Bv.z + u3x; dy = Bv.w + u3y; const float q3 = fmaf(dy, dy, dx * dx);
                const float d = (__builtin_amdgcn_sqrtf(q0) + __builtin_amdgcn_sqrtf(q1)) +
                                (__builtin_amdgcn_sqrtf(q2) + __builtin_amdgcn_sqrtf(q3));
                const bool upd = (d < bestd) || (d == bestd && n < bestn);
                bestd = upd ? d : bestd;
                bestn = upd ? n : bestn;
            }
        }

        // exact argmin across wave: DPP min on d-bits, then lowest index among minima
        const unsigned dbits = BC(unsigned, bestd);
        const unsigned dminb = wave_min_u32(dbits);
        const unsigned candn = (dbits == dminb) ? (unsigned)bestn : 0x7fffffffu;
        const int nSel = (int)wave_min_u32(candn);

        // selected contour in global frame (exact f32 codebook from L2)
        const float4 A  = gsrc[2 * nSel];
        const float4 Bv = gsrc[2 * nSel + 1];
        const float c0x = A.x  * rc - A.y  * rs + cpx, c0y = A.x  * rs + A.y  * rc + cpy;
        const float c1x = A.z  * rc - A.w  * rs + cpx, c1y = A.z  * rs + A.w  * rc + cpy;
        const float c2x = Bv.x * rc - Bv.y * rs + cpx, c2y = Bv.x * rs + Bv.y * rc + cpy;
        const float c3x = Bv.z * rc - Bv.w * rs + cpx, c3y = Bv.z * rs + Bv.w * rc + cpy;

        const float npx = 0.25f * (((c0x + c1x) + c2x) + c3x);
        const float npy = 0.25f * (((c0y + c1y) + c2y) + c3y);
        const float dxx = c0x - c3x, dyy = c0y - c3y;

        // carry FIRST (critical path into next step's scan)
        cpx = npx; cpy = npy;
        const float inv = __builtin_amdgcn_rsqf(fmaf(dyy, dyy, dxx * dxx));
        rc = dxx * inv;
        rs = dyy * inv;

        if (lane == 0) {
            const int ot = b * T_STEPS + t;
            outIdx[ot]         = (float)nSel;
            outPos[2 * ot]     = npx;
            outPos[2 * ot + 1] = npy;
            outHead[ot]        = fast_atan2(dyy, dxx);
        }
    }
}

extern "C" void kernel_launch(void* const* d_in, const int* in_sizes, int n_in,
                              void* d_out, int out_size, void* d_ws, size_t ws_size,
                              hipStream_t stream) {
    const float* data = (const float*)d_in[0];
    const float* tok  = (const float*)d_in[1];
    float* out = (float*)d_out;

    const int B = in_sizes[0] / (T_STEPS * 3);   // 4096
    const int grid = (B + WAVES_PER_BLOCK - 1) / WAVES_PER_BLOCK;

    tokenizer_kernel<<<grid, BLOCK, 0, stream>>>(data, tok, out, B);
}